// Round 1
// baseline (184.832 us; speedup 1.0000x reference)
//
#include <hip/hip_runtime.h>
#include <math.h>

#define BB 128
#define LL 512
#define KK 8
#define DD 300
#define D4 75            // D in fp16-quad (8B) units: 300 = 75*4
#define CC 14
#define STREAMS 4
#define L_PER_STREAM 8
#define L_PER_BLOCK 32   // STREAMS * L_PER_STREAM
#define UNROLL 2
#define NUM_LC (LL / L_PER_BLOCK)   // 16 partials per b

#define R_F4_ELEMS ((4905 * 300) / 4)   // 367875

typedef _Float16 h2 __attribute__((ext_vector_type(2)));
typedef _Float16 h4 __attribute__((ext_vector_type(4)));
typedef float    f4 __attribute__((ext_vector_type(4)));

// prep: convert R fp32 -> fp16 table (2.94 MB, per-XCD-L2-resident).
// One f4 (4 floats) -> one h4 (8B store). Byte layout identical to before:
// row r, elem d at byte r*600 + 2*d.
__global__ __launch_bounds__(256) void prep(
    const f4* __restrict__ R4, h4* __restrict__ R16)
{
    const int i = blockIdx.x * 256 + threadIdx.x;
    if (i < R_F4_ELEMS) {
        const f4 f = __builtin_nontemporal_load(R4 + i);
        h4 o;
        o.x = (_Float16)f.x; o.y = (_Float16)f.y;
        o.z = (_Float16)f.z; o.w = (_Float16)f.w;
        R16[i] = o;   // plain store: let it land in L2/LLC for gnn_agg
    }
}

// Block = 32 l's, 320 threads = 4 streams of 75 lanes (94% active).
// Each lane owns one 8B fp16-quad of D (dwordx2 gathers: half the load
// instructions of the 4B layout). Phase 0: 256 threads gather E (random,
// HBM, nt) + stage all slave/master row-offsets into LDS (stream id varies
// within a wave, so indices can't stay scalar -> LDS broadcast instead).
// Phase 1: per-stream 8 l's, packed-fp16 mul/max, fp32 accumulate.
// Phase 2: cross-stream LDS reduction -> ONE partial per (lc,b) instead of
// four (partial buffer 19.6 MB -> 4.9 MB round trip).
__global__ __launch_bounds__(320, 4) void gnn_agg(
    const int* __restrict__ master, const int* __restrict__ slaves,
    const int* __restrict__ edges, const float* __restrict__ E,
    const float* __restrict__ N, const h4* __restrict__ Rv,
    f4* __restrict__ Xp)
{
    const int b  = blockIdx.x;
    const int lc = blockIdx.y;
    const int t  = threadIdx.x;
    const int bl0 = b * LL + lc * L_PER_BLOCK;

    __shared__ int   olds[L_PER_BLOCK][9];      // [l][k]=slave off, [l][8]=master off
    __shared__ int   ebuf[L_PER_BLOCK * KK];    // packed h2(ev,ev)
    __shared__ float nnbuf[L_PER_BLOCK];
    __shared__ f4    sred[STREAMS][D4];         // cross-stream reduction

    if (t < L_PER_BLOCK * KK) {                 // 256 lanes: E gather + slave offs
        const int eidx = __builtin_nontemporal_load(edges + bl0 * KK + t);
        const _Float16 ev = (_Float16)__builtin_nontemporal_load(E + eidx);
        h2 p; p.x = ev; p.y = ev;
        ebuf[t] = __builtin_bit_cast(int, p);
        const int sn = __builtin_nontemporal_load(slaves + bl0 * KK + t);
        olds[t >> 3][t & 7] = sn * D4;
    } else if (t < L_PER_BLOCK * KK + L_PER_BLOCK) {   // 32 lanes: master + gate
        const int l = t - L_PER_BLOCK * KK;
        const int m = __builtin_nontemporal_load(master + bl0 + l);
        olds[l][8] = m * D4;
        nnbuf[l]   = N[m];
    }
    __syncthreads();

    const bool act = (t < STREAMS * D4);        // 300 active lanes
    const int  s   = act ? t / D4 : 0;
    const int  pos = t - s * D4;

    if (act) {
        const int ls0 = s * L_PER_STREAM;
        float a0 = 0.f, a1 = 0.f, a2 = 0.f, a3 = 0.f;

        for (int lg = 0; lg < L_PER_STREAM; lg += UNROLL) {
            int   off[UNROLL][9], ev[UNROLL][KK];
            float nn[UNROLL];
#pragma unroll
            for (int u = 0; u < UNROLL; ++u) {
                const int l = ls0 + lg + u;
#pragma unroll
                for (int k = 0; k < 9; ++k)  off[u][k] = olds[l][k];
#pragma unroll
                for (int k = 0; k < KK; ++k) ev[u][k]  = ebuf[l * KK + k];
                nn[u] = nnbuf[l];
            }

            h4 r[UNROLL][KK], rm[UNROLL];
#pragma unroll
            for (int u = 0; u < UNROLL; ++u) {
#pragma unroll
                for (int k = 0; k < KK; ++k)
                    r[u][k] = Rv[off[u][k] + pos];      // global_load_dwordx2
                rm[u] = Rv[off[u][8] + pos];
            }

#pragma unroll
            for (int u = 0; u < UNROLL; ++u) {
                h2 e0 = __builtin_bit_cast(h2, ev[u][0]);
                h4 e4 = {e0.x, e0.y, e0.x, e0.y};
                h4 mx = r[u][0] * e4;
#pragma unroll
                for (int k = 1; k < KK; ++k) {
                    h2 ek2 = __builtin_bit_cast(h2, ev[u][k]);
                    h4 ek  = {ek2.x, ek2.y, ek2.x, ek2.y};
                    mx = __builtin_elementwise_max(mx, r[u][k] * ek);
                }
                const float n = nn[u], g = 1.f - n;
                a0 = fmaf(g, (float)mx.x, fmaf(n, (float)rm[u].x, a0));
                a1 = fmaf(g, (float)mx.y, fmaf(n, (float)rm[u].y, a1));
                a2 = fmaf(g, (float)mx.z, fmaf(n, (float)rm[u].z, a2));
                a3 = fmaf(g, (float)mx.w, fmaf(n, (float)rm[u].w, a3));
            }
        }
        f4 v; v.x = a0; v.y = a1; v.z = a2; v.w = a3;
        sred[s][pos] = v;
    }
    __syncthreads();

    if (t < D4) {
        const f4 v0 = sred[0][t], v1 = sred[1][t], v2 = sred[2][t], v3 = sred[3][t];
        f4 v;
        v.x = (v0.x + v1.x) + (v2.x + v3.x);
        v.y = (v0.y + v1.y) + (v2.y + v3.y);
        v.z = (v0.z + v1.z) + (v2.z + v3.z);
        v.w = (v0.w + v1.w) + (v2.w + v3.w);
        __builtin_nontemporal_store(v, Xp + (lc * BB + b) * D4 + t);
    }
}

// Reduce 16 partials -> x[b,:], then FC (300->14) + ReLU + softmax.
__global__ __launch_bounds__(320) void fc_softmax(
    const f4* __restrict__ Xp, const float* __restrict__ W,
    const float* __restrict__ bias, float* __restrict__ out)
{
    const int b = blockIdx.x;
    const int t = threadIdx.x;
    __shared__ __align__(16) float sx[DD];
    __shared__ float h[CC];

    if (t < D4) {
        f4 a = {0.f, 0.f, 0.f, 0.f};
        const f4* p = Xp + b * D4 + t;
#pragma unroll
        for (int lc = 0; lc < NUM_LC; ++lc) {
            const f4 v = __builtin_nontemporal_load(p + lc * (BB * D4));
            a.x += v.x; a.y += v.y; a.z += v.z; a.w += v.w;
        }
        ((f4*)sx)[t] = a;
    }
    __syncthreads();

    const int c = t >> 4;
    const int j = t & 15;
    if (c < CC) {
        float acc = 0.f;
        const float* w = W + c * DD;
        for (int d = j; d < DD; d += 16) acc += sx[d] * w[d];
#pragma unroll
        for (int off = 8; off > 0; off >>= 1) acc += __shfl_down(acc, off, 16);
        if (j == 0) h[c] = fmaxf(acc + bias[c], 0.f);
    }
    __syncthreads();
    if (t < CC) {
        float mx = -INFINITY;
#pragma unroll
        for (int i = 0; i < CC; ++i) mx = fmaxf(mx, h[i]);
        float ssum = 0.f;
#pragma unroll
        for (int i = 0; i < CC; ++i) ssum += expf(h[i] - mx);
        out[b * CC + t] = expf(h[t] - mx) / ssum;
    }
}

extern "C" void kernel_launch(void* const* d_in, const int* in_sizes, int n_in,
                              void* d_out, int out_size, void* d_ws, size_t ws_size,
                              hipStream_t stream) {
    const int*   master = (const int*)d_in[0];
    const int*   slaves = (const int*)d_in[1];
    const int*   edges  = (const int*)d_in[2];
    const float* R      = (const float*)d_in[3];
    const float* E      = (const float*)d_in[4];
    const float* N      = (const float*)d_in[5];
    const float* W      = (const float*)d_in[6];
    const float* bias   = (const float*)d_in[7];
    float* out = (float*)d_out;

    // ws layout (bytes): R16 [2,943,104] | X_part [NUM_LC*BB*DD*4 = 2,457,600]
    char* ws  = (char*)d_ws;
    h4*   R16 = (h4*)ws;
    f4*   Xp  = (f4*)(ws + 2943104);

    prep<<<(R_F4_ELEMS + 255) / 256, 256, 0, stream>>>((const f4*)R, R16);

    dim3 grid(BB, NUM_LC);
    gnn_agg<<<grid, STREAMS * 80, 0, stream>>>(master, slaves, edges, E, N, R16, Xp);

    fc_softmax<<<BB, 320, 0, stream>>>(Xp, W, bias, out);
}